// Round 3
// baseline (5386.523 us; speedup 1.0000x reference)
//
#include <hip/hip_runtime.h>
#include <math.h>

#define N_NODES 200000
#define H_CH    128
#define GRP     64          // channel group width (2 groups of 64)
#define NNZ_E   3200000
#define K_DEG   15
#define DEG_BINS 64

// ---------- softmax over 16 logits ----------
__global__ void softmax_k(const float* __restrict__ logits, float* __restrict__ w) {
    if (threadIdx.x == 0) {
        float m = -1e30f;
        for (int i = 0; i <= K_DEG; ++i) m = fmaxf(m, logits[i]);
        float e[K_DEG + 1];
        float s = 0.f;
        for (int i = 0; i <= K_DEG; ++i) { e[i] = expf(logits[i] - m); s += e[i]; }
        float inv = 1.0f / s;
        for (int i = 0; i <= K_DEG; ++i) w[i] = e[i] * inv;
    }
}

// ---------- CSR build pass 1: per-edge rank within row (fused histogram) ----------
__global__ void rank_k(const int* __restrict__ row, int* __restrict__ counts,
                       int* __restrict__ rank, int nnz) {
    int i = blockIdx.x * blockDim.x + threadIdx.x;
    if (i < nnz) rank[i] = atomicAdd(&counts[row[i]], 1);
}

// ---------- CSR build: hierarchical exclusive scan (tile = 2048) ----------
__global__ void scan1_k(const int* __restrict__ counts, int* __restrict__ out,
                        int* __restrict__ partials, int n) {
    __shared__ int sm[256];
    int tbase = blockIdx.x * 2048 + threadIdx.x * 8;
    int v[8];
    int tsum = 0;
#pragma unroll
    for (int j = 0; j < 8; ++j) {
        int i = tbase + j;
        int c = (i < n) ? counts[i] : 0;
        v[j] = tsum;
        tsum += c;
    }
    sm[threadIdx.x] = tsum;
    __syncthreads();
    int incl = tsum;
    for (int off = 1; off < 256; off <<= 1) {
        int t = (threadIdx.x >= (unsigned)off) ? sm[threadIdx.x - off] : 0;
        __syncthreads();
        incl += t;
        sm[threadIdx.x] = incl;
        __syncthreads();
    }
    int texcl = incl - tsum;
    if (threadIdx.x == 255) partials[blockIdx.x] = incl;
#pragma unroll
    for (int j = 0; j < 8; ++j) {
        int i = tbase + j;
        if (i < n) out[i] = texcl + v[j];
    }
}

__global__ void scan2_k(int* partials, int nb, int* row_ptr, int n, int total) {
    __shared__ int sm[128];
    int v = (threadIdx.x < (unsigned)nb) ? partials[threadIdx.x] : 0;
    sm[threadIdx.x] = v;
    __syncthreads();
    int incl = v;
    for (int off = 1; off < 128; off <<= 1) {
        int t = (threadIdx.x >= (unsigned)off) ? sm[threadIdx.x - off] : 0;
        __syncthreads();
        incl += t;
        sm[threadIdx.x] = incl;
        __syncthreads();
    }
    if (threadIdx.x < (unsigned)nb) partials[threadIdx.x] = incl - v;
    if (threadIdx.x == 0) row_ptr[n] = total;
}

__global__ void scan3_k(int* __restrict__ row_ptr, const int* __restrict__ partials, int n) {
    int off = partials[blockIdx.x];
    int tbase = blockIdx.x * 2048 + threadIdx.x * 8;
#pragma unroll
    for (int j = 0; j < 8; ++j) {
        int i = tbase + j;
        if (i < n) row_ptr[i] += off;
    }
}

// ---------- CSR build pass 2: scatter with precomputed rank (no atomics) ----------
__global__ void scatter2_k(const int* __restrict__ row, const int* __restrict__ col,
                           const float* __restrict__ vals, const int* __restrict__ rank,
                           const int* __restrict__ row_ptr, int2* __restrict__ csr, int nnz) {
    int i = blockIdx.x * blockDim.x + threadIdx.x;
    if (i < nnz) {
        int r = row[i];
        int p = row_ptr[r] + rank[i];
        int2 cv;
        cv.x = col[i];
        cv.y = __float_as_int(vals[i]);
        csr[p] = cv;
    }
}

// ---------- degree-sorted permutation (descending degree) ----------
__global__ void dhist_k(const int* __restrict__ counts, int* __restrict__ dhist, int n) {
    __shared__ int h[DEG_BINS];
    if (threadIdx.x < DEG_BINS) h[threadIdx.x] = 0;
    __syncthreads();
    int i = blockIdx.x * blockDim.x + threadIdx.x;
    if (i < n) {
        int d = counts[i];
        int b = (d < DEG_BINS) ? (DEG_BINS - 1 - d) : 0;
        atomicAdd(&h[b], 1);
    }
    __syncthreads();
    if (threadIdx.x < DEG_BINS) atomicAdd(&dhist[threadIdx.x], h[threadIdx.x]);
}

__global__ void dscan_k(const int* __restrict__ dhist, int* __restrict__ dbase) {
    if (threadIdx.x == 0) {
        int s = 0;
        for (int b = 0; b < DEG_BINS; ++b) { dbase[b] = s; s += dhist[b]; }
    }
}

__global__ void dperm_k(const int* __restrict__ counts, const int* __restrict__ dbase,
                        int* __restrict__ dcount, int* __restrict__ perm, int n) {
    int i = blockIdx.x * blockDim.x + threadIdx.x;
    if (i < n) {
        int d = counts[i];
        int b = (d < DEG_BINS) ? (DEG_BINS - 1 - d) : 0;
        int p = dbase[b] + atomicAdd(&dcount[b], 1);
        perm[p] = i;
    }
}

// ---------- first fused kernel (per 64-ch group) ----------
// S = spmm(x_g); T1_g = S - x_g (compact);
// out_g = -(w0*x_g + w1*T1_g) + alpha*(x_g - 0.5*S)
__global__ __launch_bounds__(256) void first_k(
    const int* __restrict__ rp, const int2* __restrict__ csr, const int* __restrict__ perm,
    const float* __restrict__ x, float* __restrict__ T1g, float* __restrict__ out,
    const float* __restrict__ w, const float* __restrict__ alpha_p, int goff) {
    int wid = blockIdx.x * 4 + (threadIdx.x >> 6);
    if (wid >= N_NODES) return;
    int r = __builtin_amdgcn_readfirstlane(perm[wid]);
    int lane = threadIdx.x & 63;
    const float* base = x + goff + lane;      // gather x[col*128 + goff + lane]
    int e0 = rp[r], e1 = rp[r + 1];
    float a0 = 0.f, a1 = 0.f, a2 = 0.f, a3 = 0.f;
    float a4 = 0.f, a5 = 0.f, a6 = 0.f, a7 = 0.f;
    int e = e0;
    for (; e + 8 <= e1; e += 8) {
        int2 c0 = csr[e],     c1 = csr[e + 1], c2 = csr[e + 2], c3 = csr[e + 3];
        int2 c4 = csr[e + 4], c5 = csr[e + 5], c6 = csr[e + 6], c7 = csr[e + 7];
        a0 = fmaf(__int_as_float(c0.y), base[(size_t)c0.x * H_CH], a0);
        a1 = fmaf(__int_as_float(c1.y), base[(size_t)c1.x * H_CH], a1);
        a2 = fmaf(__int_as_float(c2.y), base[(size_t)c2.x * H_CH], a2);
        a3 = fmaf(__int_as_float(c3.y), base[(size_t)c3.x * H_CH], a3);
        a4 = fmaf(__int_as_float(c4.y), base[(size_t)c4.x * H_CH], a4);
        a5 = fmaf(__int_as_float(c5.y), base[(size_t)c5.x * H_CH], a5);
        a6 = fmaf(__int_as_float(c6.y), base[(size_t)c6.x * H_CH], a6);
        a7 = fmaf(__int_as_float(c7.y), base[(size_t)c7.x * H_CH], a7);
    }
    for (; e + 4 <= e1; e += 4) {
        int2 c0 = csr[e], c1 = csr[e + 1], c2 = csr[e + 2], c3 = csr[e + 3];
        a0 = fmaf(__int_as_float(c0.y), base[(size_t)c0.x * H_CH], a0);
        a1 = fmaf(__int_as_float(c1.y), base[(size_t)c1.x * H_CH], a1);
        a2 = fmaf(__int_as_float(c2.y), base[(size_t)c2.x * H_CH], a2);
        a3 = fmaf(__int_as_float(c3.y), base[(size_t)c3.x * H_CH], a3);
    }
    for (; e < e1; ++e) {
        int2 cv = csr[e];
        a0 = fmaf(__int_as_float(cv.y), base[(size_t)cv.x * H_CH], a0);
    }
    float s = ((a0 + a1) + (a2 + a3)) + ((a4 + a5) + (a6 + a7));
    size_t idxg = (size_t)r * GRP + lane;
    size_t idxf = (size_t)r * H_CH + goff + lane;
    float xr = x[idxf];
    float w0 = w[0], w1 = w[1], al = alpha_p[0];
    float t1 = s - xr;
    float o = -(w0 * xr + w1 * t1) + al * (xr - 0.5f * s);
    T1g[idxg] = t1;
    out[idxf] = o;
}

// ---------- Chebyshev step (per 64-ch group) ----------
// y = spmm(Tcur); Tn = 2*(y - Tcur) - Tprev; out -= w[k]*Tn; Tnext = Tn
__global__ __launch_bounds__(256) void cheb_k(
    const int* __restrict__ rp, const int2* __restrict__ csr, const int* __restrict__ perm,
    const float* __restrict__ Tcur, const float* TprevBase, int tprevStride,
    float* Tnext, float* __restrict__ out,
    const float* __restrict__ w, int k, int goff) {
    int wid = blockIdx.x * 4 + (threadIdx.x >> 6);
    if (wid >= N_NODES) return;
    int r = __builtin_amdgcn_readfirstlane(perm[wid]);
    int lane = threadIdx.x & 63;
    const float* base = Tcur + lane;          // gather Tcur[col*64 + lane]
    int e0 = rp[r], e1 = rp[r + 1];
    float a0 = 0.f, a1 = 0.f, a2 = 0.f, a3 = 0.f;
    float a4 = 0.f, a5 = 0.f, a6 = 0.f, a7 = 0.f;
    int e = e0;
    for (; e + 8 <= e1; e += 8) {
        int2 c0 = csr[e],     c1 = csr[e + 1], c2 = csr[e + 2], c3 = csr[e + 3];
        int2 c4 = csr[e + 4], c5 = csr[e + 5], c6 = csr[e + 6], c7 = csr[e + 7];
        a0 = fmaf(__int_as_float(c0.y), base[(size_t)c0.x * GRP], a0);
        a1 = fmaf(__int_as_float(c1.y), base[(size_t)c1.x * GRP], a1);
        a2 = fmaf(__int_as_float(c2.y), base[(size_t)c2.x * GRP], a2);
        a3 = fmaf(__int_as_float(c3.y), base[(size_t)c3.x * GRP], a3);
        a4 = fmaf(__int_as_float(c4.y), base[(size_t)c4.x * GRP], a4);
        a5 = fmaf(__int_as_float(c5.y), base[(size_t)c5.x * GRP], a5);
        a6 = fmaf(__int_as_float(c6.y), base[(size_t)c6.x * GRP], a6);
        a7 = fmaf(__int_as_float(c7.y), base[(size_t)c7.x * GRP], a7);
    }
    for (; e + 4 <= e1; e += 4) {
        int2 c0 = csr[e], c1 = csr[e + 1], c2 = csr[e + 2], c3 = csr[e + 3];
        a0 = fmaf(__int_as_float(c0.y), base[(size_t)c0.x * GRP], a0);
        a1 = fmaf(__int_as_float(c1.y), base[(size_t)c1.x * GRP], a1);
        a2 = fmaf(__int_as_float(c2.y), base[(size_t)c2.x * GRP], a2);
        a3 = fmaf(__int_as_float(c3.y), base[(size_t)c3.x * GRP], a3);
    }
    for (; e < e1; ++e) {
        int2 cv = csr[e];
        a0 = fmaf(__int_as_float(cv.y), base[(size_t)cv.x * GRP], a0);
    }
    float s = ((a0 + a1) + (a2 + a3)) + ((a4 + a5) + (a6 + a7));
    size_t idxg = (size_t)r * GRP + lane;
    size_t idxf = (size_t)r * H_CH + goff + lane;
    float tc = Tcur[idxg];
    float tp = TprevBase[(size_t)r * tprevStride + lane];
    float wk = w[k];
    float tn = 2.0f * (s - tc) - tp;
    float o = out[idxf];
    o -= wk * tn;
    out[idxf] = o;
    Tnext[idxg] = tn;
}

extern "C" void kernel_launch(void* const* d_in, const int* in_sizes, int n_in,
                              void* d_out, int out_size, void* d_ws, size_t ws_size,
                              hipStream_t stream) {
    const float* x      = (const float*)d_in[0];
    const float* vals   = (const float*)d_in[1];
    const float* logits = (const float*)d_in[2];
    const float* alpha  = (const float*)d_in[3];
    const int*   erow   = (const int*)d_in[4];
    const int*   ecol   = (const int*)d_in[5];
    float* out = (float*)d_out;

    const size_t NG = (size_t)N_NODES * GRP;       // per-group state elements
    float* bufA    = (float*)d_ws;                 // N x 64
    float* bufB    = bufA + NG;                    // N x 64
    int2*  csr     = (int2*)(bufB + NG);           // packed col+val, NNZ
    int*   row_ptr = (int*)(csr + NNZ_E);          // N+1
    int*   counts  = row_ptr + (N_NODES + 1);      // N (degrees after rank_k)
    int*   rank    = counts + N_NODES;             // NNZ
    int*   perm    = rank + NNZ_E;                 // N
    int*   partials= perm + N_NODES;               // 128
    int*   dhist   = partials + 128;               // 64
    int*   dbase   = dhist + DEG_BINS;             // 64
    int*   dcount  = dbase + DEG_BINS;             // 64
    float* w_buf   = (float*)(dcount + DEG_BINS);  // 16

    hipMemsetAsync(counts, 0, N_NODES * sizeof(int), stream);
    hipMemsetAsync(dhist, 0, DEG_BINS * sizeof(int), stream);
    hipMemsetAsync(dcount, 0, DEG_BINS * sizeof(int), stream);
    softmax_k<<<1, 64, 0, stream>>>(logits, w_buf);

    rank_k<<<(NNZ_E + 255) / 256, 256, 0, stream>>>(erow, counts, rank, NNZ_E);

    const int TILE = 2048;
    int nblk = (N_NODES + TILE - 1) / TILE;        // 98
    scan1_k<<<nblk, 256, 0, stream>>>(counts, row_ptr, partials, N_NODES);
    scan2_k<<<1, 128, 0, stream>>>(partials, nblk, row_ptr, N_NODES, NNZ_E);
    scan3_k<<<nblk, 256, 0, stream>>>(row_ptr, partials, N_NODES);

    // degree-descending permutation from counts (= degrees)
    dhist_k<<<(N_NODES + 255) / 256, 256, 0, stream>>>(counts, dhist, N_NODES);
    dscan_k<<<1, 64, 0, stream>>>(dhist, dbase);
    dperm_k<<<(N_NODES + 255) / 256, 256, 0, stream>>>(counts, dbase, dcount, perm, N_NODES);

    scatter2_k<<<(NNZ_E + 255) / 256, 256, 0, stream>>>(erow, ecol, vals, rank, row_ptr,
                                                        csr, NNZ_E);

    int grid = (N_NODES + 3) / 4;                  // 4 rows (waves) per 256-thread block

    for (int g = 0; g < H_CH / GRP; ++g) {
        int goff = g * GRP;
        first_k<<<grid, 256, 0, stream>>>(row_ptr, csr, perm, x, bufB, out, w_buf, alpha, goff);
        cheb_k<<<grid, 256, 0, stream>>>(row_ptr, csr, perm, bufB, x + goff, H_CH, bufA,
                                         out, w_buf, 2, goff);
        float* Tcur = bufA;
        float* Tprev = bufB;
        for (int k = 3; k <= K_DEG; ++k) {
            cheb_k<<<grid, 256, 0, stream>>>(row_ptr, csr, perm, Tcur, Tprev, GRP, Tprev,
                                             out, w_buf, k, goff);
            float* t = Tcur; Tcur = Tprev; Tprev = t;
        }
    }
}